// Round 3
// baseline (501.339 us; speedup 1.0000x reference)
//
#include <hip/hip_runtime.h>
#include <hip/hip_bf16.h>

// QuantizedLinear: y[t,o] = scale * sum_i x[t,i]*W[o,i] + bias[o]
// M=8192 (tokens), N=4096 (d_out), K=4096 (d_in).
//
// Round 6: r5 structure (256x256 8-phase, counted vmcnt, T1/T2/T5) +
//  (a) inline-asm s_barrier in the GEMM main loop. Theory: the backend
//      inserts s_waitcnt vmcnt(0) before the *builtin* s_barrier when
//      global_load_lds ops are outstanding, silently degrading the counted
//      vmcnt(6) pipeline to drain-0 (matches measured m200-level 44%
//      MfmaUtil). asm barriers are opaque to the waitcnt pass; all
//      cross-wave hazards are covered by our explicit vmcnt/lgkmcnt waits
//      (ledger re-audited).
//  (b) epilogue: per-wave 16x16 LDS transpose (reusing the staging LDS after
//      the final barrier) -> global_store_dwordx4 + float4 bias loads,
//      replacing 128 scalar stores/thread.

typedef __bf16 bf16_t;
typedef __attribute__((ext_vector_type(8))) __bf16 bf16x8;
typedef __attribute__((ext_vector_type(4))) __bf16 bf16x4;
typedef __attribute__((ext_vector_type(4))) float f32x4;

#define BM 128
#define BN 128
#define BK 32

#define LDS_U32(p) ((__attribute__((address_space(3))) uint32_t*)(p))
#define GLB_U32(p) ((const __attribute__((address_space(1))) uint32_t*)(p))

// Raw barrier: opaque to the backend waitcnt pass (no implicit vmcnt drain).
#define ASM_BARRIER() asm volatile("s_barrier" ::: "memory")

// ---------------- phase 1: fp32 -> bf16 convert (both X and W) -------------
__global__ __launch_bounds__(256)
void cvt2_f32_bf16(const float* __restrict__ xsrc, bf16_t* __restrict__ xdst, long xn8,
                   const float* __restrict__ wsrc, bf16_t* __restrict__ wdst, long wn8)
{
    long i = (long)blockIdx.x * 256 + threadIdx.x;   // float8 index
    const float4* s;
    bf16x8* d;
    if (i < xn8) {
        s = (const float4*)xsrc; d = (bf16x8*)xdst;
    } else {
        i -= xn8;
        if (i >= wn8) return;
        s = (const float4*)wsrc; d = (bf16x8*)wdst;
    }
    float4 a = s[2 * i];
    float4 b = s[2 * i + 1];
    bf16x8 o = { (bf16_t)a.x, (bf16_t)a.y, (bf16_t)a.z, (bf16_t)a.w,
                 (bf16_t)b.x, (bf16_t)b.y, (bf16_t)b.z, (bf16_t)b.w };
    d[i] = o;
}

// ---------------- phase 2: 256x256 8-phase bf16 MFMA GEMM ------------------
__global__ __launch_bounds__(512, 2)
void ql_gemm_256_8ph(const bf16_t* __restrict__ X,   // [M,K] bf16
                     const bf16_t* __restrict__ W,   // [N,K] bf16
                     const float* __restrict__ bias, // [N]
                     const float* __restrict__ scale_p,
                     float* __restrict__ Y,          // [M,N]
                     int M, int N, int K)
{
    // [buf][mat(0=A,1=B)][kk(32-col block)][row 0..255][col 0..31] = 128 KiB
    __shared__ alignas(16) bf16_t lds[2][2][2][256][32];
    static_assert(sizeof(lds) == 131072, "LDS layout");

    const int tid    = threadIdx.x;
    const int lane   = tid & 63;
    const int wid    = tid >> 6;          // 0..7
    const int wr     = wid >> 2;          // 0..1  (M half)
    const int wc     = wid & 3;           // 0..3  (N quarter)
    const int r_lane = lane & 15;
    const int quad   = lane >> 4;
    // fragment read col: source col-group `quad` of row (16-aligned base + r_lane)
    const int rd_col = (quad ^ ((r_lane >> 1) & 3)) * 8;

    // staging lane geometry: lane l writes LDS byte l*16 of a 1KB block
    // = row (l>>2), slot-group (l&3). slot-group g holds source col-group
    // g ^ ((row>>1)&3)  ->  source col-group below.
    const int st_row = lane >> 2;                            // 0..15
    const int st_col = ((lane & 3) ^ ((lane >> 3) & 3)) * 8; // within 32-col blk

    // per-wave 16-row block bases for the four half-tiles (16 KB each):
    const int rbA1 = (wid & 3) * 16 + wr * 128;
    const int rbA2 = rbA1 + 64;
    const int rbB1 = (wid & 1) * 16 + (wid >> 1) * 64;
    const int rbB2 = rbB1 + 32;

    // XCD-aware bijective block swizzle; consecutive wgs share the A panel.
    int bid = blockIdx.x;
    const int nbn = N >> 8;
    const int nwg = gridDim.x;
    if ((nwg & 7) == 0) { const int q = nwg >> 3; bid = (bid & 7) * q + (bid >> 3); }
    const int m0 = (bid / nbn) << 8;
    const int n0 = (bid % nbn) << 8;

    const int NT = K >> 6;   // number of 64-wide K tiles

#define STAGE(matA, rb, bufv, tv)                                                   \
    do {                                                                            \
        const bf16_t* _s = (matA) ? W : X;                                          \
        const int _r0    = (matA) ? n0 : m0;                                        \
        const size_t _go = (size_t)(_r0 + (rb) + st_row) * K                        \
                         + (size_t)(tv) * 64 + st_col;                              \
        __builtin_amdgcn_global_load_lds(GLB_U32(_s + _go),                         \
            LDS_U32(&lds[bufv][matA][0][rb][0]), 16, 0, 0);                         \
        __builtin_amdgcn_global_load_lds(GLB_U32(_s + _go + 32),                    \
            LDS_U32(&lds[bufv][matA][1][rb][0]), 16, 0, 0);                         \
    } while (0)

    f32x4 acc[8][4];
#pragma unroll
    for (int i = 0; i < 8; i++)
#pragma unroll
        for (int j = 0; j < 4; j++)
            acc[i][j] = (f32x4)0.0f;

    // ---- prologue: tile0 fully + tile1 first 3 half-tiles -----------------
    STAGE(0, rbA1, 0, 0);
    STAGE(1, rbB1, 0, 0);
    STAGE(1, rbB2, 0, 0);
    STAGE(0, rbA2, 0, 0);
    if (NT > 1) {
        STAGE(0, rbA1, 1, 1);
        STAGE(1, rbB1, 1, 1);
        STAGE(1, rbB2, 1, 1);
        asm volatile("s_waitcnt vmcnt(6)" ::: "memory");  // tile0 landed
    } else {
        asm volatile("s_waitcnt vmcnt(0)" ::: "memory");
    }
    ASM_BARRIER();

    bf16x8 aA[4][2], aB0[2][2], aB1[2][2];

    for (int t = 0; t < NT; ++t) {
        const int buf = t & 1;

        // ================= phase 0: aA(i0-3) + aB0, Q0 =====================
#pragma unroll
        for (int i = 0; i < 4; i++)
#pragma unroll
            for (int kk = 0; kk < 2; kk++)
                aA[i][kk] = *(const bf16x8*)&lds[buf][0][kk][wr * 128 + i * 16 + r_lane][rd_col];
#pragma unroll
        for (int j = 0; j < 2; j++)
#pragma unroll
            for (int kk = 0; kk < 2; kk++)
                aB0[j][kk] = *(const bf16x8*)&lds[buf][1][kk][wc * 64 + j * 16 + r_lane][rd_col];
        if (t + 1 < NT) STAGE(0, rbA2, buf ^ 1, t + 1);   // last HT of tile t+1
        ASM_BARRIER();
        asm volatile("s_waitcnt lgkmcnt(0)" ::: "memory");
        __builtin_amdgcn_s_setprio(1);
#pragma unroll
        for (int i = 0; i < 4; i++)
#pragma unroll
            for (int j = 0; j < 2; j++)
#pragma unroll
                for (int kk = 0; kk < 2; kk++)
                    acc[i][j] = __builtin_amdgcn_mfma_f32_16x16x32_bf16(
                        aA[i][kk], aB0[j][kk], acc[i][j], 0, 0, 0);
        __builtin_amdgcn_s_setprio(0);
        ASM_BARRIER();

        // ================= phase 1: aB1, Q1 ================================
#pragma unroll
        for (int j = 0; j < 2; j++)
#pragma unroll
            for (int kk = 0; kk < 2; kk++)
                aB1[j][kk] = *(const bf16x8*)&lds[buf][1][kk][wc * 64 + (2 + j) * 16 + r_lane][rd_col];
        if (t + 2 < NT) STAGE(0, rbA1, buf, t + 2);       // A1 region dead after p0
        ASM_BARRIER();
        asm volatile("s_waitcnt lgkmcnt(0)" ::: "memory");
        __builtin_amdgcn_s_setprio(1);
#pragma unroll
        for (int i = 0; i < 4; i++)
#pragma unroll
            for (int j = 0; j < 2; j++)
#pragma unroll
                for (int kk = 0; kk < 2; kk++)
                    acc[i][2 + j] = __builtin_amdgcn_mfma_f32_16x16x32_bf16(
                        aA[i][kk], aB1[j][kk], acc[i][2 + j], 0, 0, 0);
        __builtin_amdgcn_s_setprio(0);
        ASM_BARRIER();

        // ================= phase 2: aA(i4-7), Q2 ===========================
#pragma unroll
        for (int i = 0; i < 4; i++)
#pragma unroll
            for (int kk = 0; kk < 2; kk++)
                aA[i][kk] = *(const bf16x8*)&lds[buf][0][kk][wr * 128 + (4 + i) * 16 + r_lane][rd_col];
        if (t + 2 < NT) STAGE(1, rbB1, buf, t + 2);       // B1 region dead after p0
        ASM_BARRIER();
        asm volatile("s_waitcnt lgkmcnt(0)" ::: "memory");
        __builtin_amdgcn_s_setprio(1);
#pragma unroll
        for (int i = 0; i < 4; i++)
#pragma unroll
            for (int j = 0; j < 2; j++)
#pragma unroll
                for (int kk = 0; kk < 2; kk++)
                    acc[4 + i][j] = __builtin_amdgcn_mfma_f32_16x16x32_bf16(
                        aA[i][kk], aB0[j][kk], acc[4 + i][j], 0, 0, 0);
        __builtin_amdgcn_s_setprio(0);
        ASM_BARRIER();

        // ================= phase 3: Q3, per-tile vmcnt wait ================
        if (t + 2 < NT) STAGE(1, rbB2, buf, t + 2);       // B2 region dead after p1
        ASM_BARRIER();
        __builtin_amdgcn_s_setprio(1);
#pragma unroll
        for (int i = 0; i < 4; i++)
#pragma unroll
            for (int j = 0; j < 2; j++)
#pragma unroll
                for (int kk = 0; kk < 2; kk++)
                    acc[4 + i][2 + j] = __builtin_amdgcn_mfma_f32_16x16x32_bf16(
                        aA[i][kk], aB1[j][kk], acc[4 + i][2 + j], 0, 0, 0);
        __builtin_amdgcn_s_setprio(0);
        // Youngest 6 outstanding loads are tile-(t+2) stages (other buffer);
        // waiting to 6 proves tile t+1 is fully landed. Tail: drain.
        if (t + 2 < NT) asm volatile("s_waitcnt vmcnt(6)" ::: "memory");
        else            asm volatile("s_waitcnt vmcnt(0)" ::: "memory");
        ASM_BARRIER();
    }
#undef STAGE

    // ---- epilogue: per-wave 16x16 LDS transpose -> dwordx4 stores ---------
    // All DMA drained (vmcnt(0)) and all waves past their last ds_read
    // (final barrier above), so the staging LDS is reusable as scratch.
    const float s = *scale_p;
    float* patch = ((float*)&lds[0][0][0][0][0]) + wid * (16 * 20); // [16][20] f32
    const int lrow = lane >> 2;        // 0..15
    const int lcg  = lane & 3;         // 0..3

#pragma unroll
    for (int j = 0; j < 4; j++) {
        const int col0 = n0 + wc * 64 + j * 16 + lcg * 4;
        const f32x4 b4 = *(const f32x4*)&bias[col0];
#pragma unroll
        for (int i = 0; i < 8; i++) {
            // scatter this lane's 4 values (4 consecutive rows, one col)
#pragma unroll
            for (int r = 0; r < 4; r++)
                patch[(quad * 4 + r) * 20 + r_lane] = acc[i][j][r];
            // gather 4 consecutive cols of one row (in-wave, LDS in-order)
            f32x4 v = *(const f32x4*)&patch[lrow * 20 + lcg * 4];
            f32x4 out = v * s + b4;
            const int row = m0 + wr * 128 + i * 16 + lrow;
            *(f32x4*)&Y[(size_t)row * N + col0] = out;
        }
    }
}

// ---------------- fallback: 128^2 DMA kernel (previous best) ---------------
__global__ __launch_bounds__(256)
void ql_gemm_bf16_dma(const bf16_t* __restrict__ X,   // [M,K] bf16
                      const bf16_t* __restrict__ W,   // [N,K] bf16
                      const float* __restrict__ bias, // [N]
                      const float* __restrict__ scale_p,
                      float* __restrict__ Y,          // [M,N]
                      int M, int N, int K)
{
    __shared__ alignas(16) bf16_t lA[BM][BK];
    __shared__ alignas(16) bf16_t lB[BN][BK];

    const int tid  = threadIdx.x;
    const int lane = tid & 63;
    const int wave = tid >> 6;            // 0..3
    const int wm   = (wave & 1) * 64;
    const int wn   = (wave >> 1) * 64;

    const int m0 = blockIdx.x * BM;
    const int n0 = blockIdx.y * BN;

    const int r_lane = lane & 15;
    const int quad   = lane >> 4;

    const int st_row = lane >> 2;
    const int st_q   = (lane & 3) ^ ((lane >> 3) & 3);
    const int st_col = st_q * 8;

    const int rd_col = (quad ^ ((r_lane >> 1) & 3)) * 8;

    f32x4 acc[4][4];
#pragma unroll
    for (int i = 0; i < 4; i++)
#pragma unroll
        for (int j = 0; j < 4; j++)
            acc[i][j] = (f32x4)0.0f;

    for (int k0 = 0; k0 < K; k0 += BK) {
#pragma unroll
        for (int i = 0; i < 2; i++) {
            const int c   = i * 4 + wave;       // chunk 0..7
            const int row = c * 16 + st_row;
            __builtin_amdgcn_global_load_lds(
                GLB_U32(X + (size_t)(m0 + row) * K + k0 + st_col),
                LDS_U32(&lA[c * 16][0]), 16, 0, 0);
            __builtin_amdgcn_global_load_lds(
                GLB_U32(W + (size_t)(n0 + row) * K + k0 + st_col),
                LDS_U32(&lB[c * 16][0]), 16, 0, 0);
        }
        __syncthreads();

        bf16x8 af[4], bfr[4];
#pragma unroll
        for (int i = 0; i < 4; i++) {
            af[i]  = *(const bf16x8*)&lA[wm + i * 16 + r_lane][rd_col];
            bfr[i] = *(const bf16x8*)&lB[wn + i * 16 + r_lane][rd_col];
        }

#pragma unroll
        for (int i = 0; i < 4; i++)
#pragma unroll
            for (int j = 0; j < 4; j++)
                acc[i][j] = __builtin_amdgcn_mfma_f32_16x16x32_bf16(
                    af[i], bfr[j], acc[i][j], 0, 0, 0);

        __syncthreads();
    }

    const float s = *scale_p;
#pragma unroll
    for (int j = 0; j < 4; j++) {
        const int col  = n0 + wn + j * 16 + r_lane;
        const float bc = bias[col];
#pragma unroll
        for (int i = 0; i < 4; i++) {
            const int rowg = m0 + wm + i * 16 + quad * 4;
#pragma unroll
            for (int r = 0; r < 4; r++)
                Y[(size_t)(rowg + r) * N + col] = acc[i][j][r] * s + bc;
        }
    }
}

// ---------------- fallback: fused-convert kernel (no workspace) ------------
__global__ __launch_bounds__(256)
void ql_gemm_bf16_fused(const float* __restrict__ X, const float* __restrict__ W,
                        const float* __restrict__ bias, const float* __restrict__ scale_p,
                        float* __restrict__ Y, int M, int N, int K)
{
    __shared__ alignas(16) bf16_t lA[BM][BK];
    __shared__ alignas(16) bf16_t lB[BN][BK];

    const int tid  = threadIdx.x;
    const int lane = tid & 63;
    const int wave = tid >> 6;
    const int wm   = (wave & 1) * 64;
    const int wn   = (wave >> 1) * 64;
    const int m0 = blockIdx.x * BM;
    const int n0 = blockIdx.y * BN;
    const int r_lane = lane & 15;
    const int quad   = lane >> 4;

    f32x4 acc[4][4];
#pragma unroll
    for (int i = 0; i < 4; i++)
#pragma unroll
        for (int j = 0; j < 4; j++) acc[i][j] = (f32x4)0.0f;

    for (int k0 = 0; k0 < K; k0 += BK) {
#pragma unroll
        for (int i = 0; i < 4; i++) {
            const int l   = tid + i * 256;
            const int row = l >> 3;
            const int c4  = (l & 7) * 4;
            const float4 xa = *(const float4*)(X + (size_t)(m0 + row) * K + k0 + c4);
            const float4 wb = *(const float4*)(W + (size_t)(n0 + row) * K + k0 + c4);
            bf16x4 xh = { (bf16_t)xa.x, (bf16_t)xa.y, (bf16_t)xa.z, (bf16_t)xa.w };
            bf16x4 wh = { (bf16_t)wb.x, (bf16_t)wb.y, (bf16_t)wb.z, (bf16_t)wb.w };
            *(bf16x4*)&lA[row][c4] = xh;
            *(bf16x4*)&lB[row][c4] = wh;
        }
        __syncthreads();
        bf16x8 af[4], bfr[4];
#pragma unroll
        for (int i = 0; i < 4; i++) {
            af[i]  = *(const bf16x8*)&lA[wm + i * 16 + r_lane][quad * 8];
            bfr[i] = *(const bf16x8*)&lB[wn + i * 16 + r_lane][quad * 8];
        }
#pragma unroll
        for (int i = 0; i < 4; i++)
#pragma unroll
            for (int j = 0; j < 4; j++)
                acc[i][j] = __builtin_amdgcn_mfma_f32_16x16x32_bf16(af[i], bfr[j], acc[i][j], 0, 0, 0);
        __syncthreads();
    }

    const float s = *scale_p;
#pragma unroll
    for (int j = 0; j < 4; j++) {
        const int col  = n0 + wn + j * 16 + r_lane;
        const float bc = bias[col];
#pragma unroll
        for (int i = 0; i < 4; i++) {
            const int rowg = m0 + wm + i * 16 + quad * 4;
#pragma unroll
            for (int r = 0; r < 4; r++)
                Y[(size_t)(rowg + r) * N + col] = acc[i][j][r] * s + bc;
        }
    }
}

extern "C" void kernel_launch(void* const* d_in, const int* in_sizes, int n_in,
                              void* d_out, int out_size, void* d_ws, size_t ws_size,
                              hipStream_t stream) {
    const float* X     = (const float*)d_in[0];
    const float* W     = (const float*)d_in[1];
    const float* bias  = (const float*)d_in[2];
    const float* scale = (const float*)d_in[3];
    float* Y           = (float*)d_out;

    const int N = in_sizes[2];
    const int K = in_sizes[1] / N;
    const int M = in_sizes[0] / K;

    const size_t x_elems = (size_t)M * K;
    const size_t w_elems = (size_t)N * K;
    const size_t need = (x_elems + w_elems) * sizeof(bf16_t);

    if (ws_size >= need) {
        bf16_t* Xb = (bf16_t*)d_ws;
        bf16_t* Wb = Xb + x_elems;
        long xn8 = (long)(x_elems / 8);
        long wn8 = (long)(w_elems / 8);
        long nthreads = xn8 + wn8;
        cvt2_f32_bf16<<<(nthreads + 255) / 256, 256, 0, stream>>>(X, Xb, xn8, W, Wb, wn8);

        if ((M % 256 == 0) && (N % 256 == 0) && (K % 64 == 0) && (N % 16 == 0) &&
            (x_elems % 8 == 0) && (w_elems % 8 == 0)) {
            dim3 grid((M / 256) * (N / 256));
            ql_gemm_256_8ph<<<grid, 512, 0, stream>>>(Xb, Wb, bias, scale, Y, M, N, K);
        } else {
            dim3 grid(M / BM, N / BN);
            ql_gemm_bf16_dma<<<grid, 256, 0, stream>>>(Xb, Wb, bias, scale, Y, M, N, K);
        }
    } else {
        dim3 grid(M / BM, N / BN);
        ql_gemm_bf16_fused<<<grid, 256, 0, stream>>>(X, W, bias, scale, Y, M, N, K);
    }
}

// Round 4
// 488.204 us; speedup vs baseline: 1.0269x; 1.0269x over previous
//
#include <hip/hip_runtime.h>
#include <hip/hip_bf16.h>

// QuantizedLinear: y[t,o] = scale * sum_i x[t,i]*W[o,i] + bias[o]
// M=8192 (tokens), N=4096 (d_out), K=4096 (d_in).
//
// Round 7: VALU-starvation attack on the 256x256 8-phase kernel.
//  Evidence: VALUBusy 18.5% @ 2 waves/SIMD ~= 230 VALU/wave/K-tile of address
//  math stealing MFMA issue slots (MfmaUtil stuck at 44%).
//  (a) running per-lane global pointers for the 4 STAGE sites (+=64/use);
//  (b) K-loop pair-unrolled with compile-time buf -> all LDS addresses fold
//      to base + immediate offset;
//  (c) blanket lgkmcnt(0) removed -- every ds_read is register-consumed by an
//      MFMA in its own phase, so the backend emits fine-grained lgkm waits
//      (race audit: reads complete before the consuming MFMA, which precedes
//      the closing barrier, which precedes the overwriting STAGE);
//  (d) epilogue reverted to the verified scalar form (r6's LDS transpose was
//      neutral and added 1M bank conflicts).

typedef __bf16 bf16_t;
typedef __attribute__((ext_vector_type(8))) __bf16 bf16x8;
typedef __attribute__((ext_vector_type(4))) __bf16 bf16x4;
typedef __attribute__((ext_vector_type(4))) float f32x4;

#define BM 128
#define BN 128
#define BK 32

#define LDS_U32(p) ((__attribute__((address_space(3))) uint32_t*)(p))
#define GLB_U32(p) ((const __attribute__((address_space(1))) uint32_t*)(p))
// Raw barrier: opaque to the waitcnt pass (no implicit drains).
#define ASM_BARRIER() asm volatile("s_barrier" ::: "memory")

// ---------------- phase 1: fp32 -> bf16 convert (both X and W) -------------
__global__ __launch_bounds__(256)
void cvt2_f32_bf16(const float* __restrict__ xsrc, bf16_t* __restrict__ xdst, long xn8,
                   const float* __restrict__ wsrc, bf16_t* __restrict__ wdst, long wn8)
{
    long i = (long)blockIdx.x * 256 + threadIdx.x;   // float8 index
    const float4* s;
    bf16x8* d;
    if (i < xn8) {
        s = (const float4*)xsrc; d = (bf16x8*)xdst;
    } else {
        i -= xn8;
        if (i >= wn8) return;
        s = (const float4*)wsrc; d = (bf16x8*)wdst;
    }
    float4 a = s[2 * i];
    float4 b = s[2 * i + 1];
    bf16x8 o = { (bf16_t)a.x, (bf16_t)a.y, (bf16_t)a.z, (bf16_t)a.w,
                 (bf16_t)b.x, (bf16_t)b.y, (bf16_t)b.z, (bf16_t)b.w };
    d[i] = o;
}

// ---------------- phase 2: 256x256 8-phase bf16 MFMA GEMM ------------------
__global__ __launch_bounds__(512, 2)
void ql_gemm_256_8ph(const bf16_t* __restrict__ X,   // [M,K] bf16
                     const bf16_t* __restrict__ W,   // [N,K] bf16
                     const float* __restrict__ bias, // [N]
                     const float* __restrict__ scale_p,
                     float* __restrict__ Y,          // [M,N]
                     int M, int N, int K)
{
    // [buf][mat(0=A,1=B)][kk(32-col block)][row 0..255][col 0..31] = 128 KiB
    __shared__ alignas(16) bf16_t lds[2][2][2][256][32];
    static_assert(sizeof(lds) == 131072, "LDS layout");

    const int tid    = threadIdx.x;
    const int lane   = tid & 63;
    const int wid    = tid >> 6;          // 0..7
    const int wr     = wid >> 2;          // 0..1  (M half)
    const int wc     = wid & 3;           // 0..3  (N quarter)
    const int r_lane = lane & 15;
    const int quad   = lane >> 4;
    const int rd_col = (quad ^ ((r_lane >> 1) & 3)) * 8;

    const int st_row = lane >> 2;                            // 0..15
    const int st_col = ((lane & 3) ^ ((lane >> 3) & 3)) * 8; // within 32-col blk

    const int rbA1 = (wid & 3) * 16 + wr * 128;
    const int rbA2 = rbA1 + 64;
    const int rbB1 = (wid & 1) * 16 + (wid >> 1) * 64;
    const int rbB2 = rbB1 + 32;

    // XCD-aware bijective block swizzle; consecutive wgs share the A panel.
    int bid = blockIdx.x;
    const int nbn = N >> 8;
    const int nwg = gridDim.x;
    if ((nwg & 7) == 0) { const int q = nwg >> 3; bid = (bid & 7) * q + (bid >> 3); }
    const int m0 = (bid / nbn) << 8;
    const int n0 = (bid % nbn) << 8;

    const int NT = K >> 6;   // 64-wide K tiles; launcher guarantees NT>=4, even

    // Running per-lane global pointers for the 4 stage sites (advance +=64/use).
    const bf16_t* pA1 = X + (size_t)(m0 + rbA1 + st_row) * K + st_col;
    const bf16_t* pA2 = X + (size_t)(m0 + rbA2 + st_row) * K + st_col;
    const bf16_t* pB1 = W + (size_t)(n0 + rbB1 + st_row) * K + st_col;
    const bf16_t* pB2 = W + (size_t)(n0 + rbB2 + st_row) * K + st_col;

#define STG(PTR, BUFC, MATC, RB)                                              \
    do {                                                                      \
        __builtin_amdgcn_global_load_lds(GLB_U32(PTR),                        \
            LDS_U32(&lds[BUFC][MATC][0][RB][0]), 16, 0, 0);                   \
        __builtin_amdgcn_global_load_lds(GLB_U32((PTR) + 32),                 \
            LDS_U32(&lds[BUFC][MATC][1][RB][0]), 16, 0, 0);                   \
    } while (0)

    f32x4 acc[8][4];
#pragma unroll
    for (int i = 0; i < 8; i++)
#pragma unroll
        for (int j = 0; j < 4; j++)
            acc[i][j] = (f32x4)0.0f;

    // ---- prologue: tile0 fully + tile1 {A1,B1,B2} (oldest 8 = tile0) ------
    STG(pA1, 0, 0, rbA1);
    STG(pB1, 0, 1, rbB1);
    STG(pB2, 0, 1, rbB2);
    STG(pA2, 0, 0, rbA2);
    STG(pA1 + 64, 1, 0, rbA1);
    STG(pB1 + 64, 1, 1, rbB1);
    STG(pB2 + 64, 1, 1, rbB2);
    pA2 += 64;    // next use stages tile1's A2 (loop t=0)
    pA1 += 128;   // next use stages tile2
    pB1 += 128;
    pB2 += 128;
    asm volatile("s_waitcnt vmcnt(6)" ::: "memory");  // tile0 landed
    ASM_BARRIER();

    bf16x8 aA[4][2], aB0[2][2], aB1[2][2];

    // One K-tile (BK=64), 4 phases. BUFC is a literal -> all LDS addresses
    // fold to base + immediate offset. WN is the p3 vmcnt level.
#define KTILE(BUFC, DOA2, DOREST, WN)                                         \
    do {                                                                      \
        /* ---- p0: read aA(rows 0-63 of wave half) + aB0; stage A2(t+1) */   \
        _Pragma("unroll") for (int i = 0; i < 4; i++)                         \
        _Pragma("unroll") for (int kk = 0; kk < 2; kk++)                      \
            aA[i][kk] = *(const bf16x8*)&lds[BUFC][0][kk][wr * 128 + i * 16 + r_lane][rd_col]; \
        _Pragma("unroll") for (int j = 0; j < 2; j++)                         \
        _Pragma("unroll") for (int kk = 0; kk < 2; kk++)                      \
            aB0[j][kk] = *(const bf16x8*)&lds[BUFC][1][kk][wc * 64 + j * 16 + r_lane][rd_col]; \
        if (DOA2) { STG(pA2, (BUFC) ^ 1, 0, rbA2); pA2 += 64; }               \
        ASM_BARRIER();                                                        \
        __builtin_amdgcn_s_setprio(1);                                        \
        _Pragma("unroll") for (int i = 0; i < 4; i++)                         \
        _Pragma("unroll") for (int j = 0; j < 2; j++)                         \
        _Pragma("unroll") for (int kk = 0; kk < 2; kk++)                      \
            acc[i][j] = __builtin_amdgcn_mfma_f32_16x16x32_bf16(              \
                aA[i][kk], aB0[j][kk], acc[i][j], 0, 0, 0);                   \
        __builtin_amdgcn_s_setprio(0);                                        \
        ASM_BARRIER();                                                        \
        /* ---- p1: read aB1; stage A1(t+2) (A1 region dead after p0) */      \
        _Pragma("unroll") for (int j = 0; j < 2; j++)                         \
        _Pragma("unroll") for (int kk = 0; kk < 2; kk++)                      \
            aB1[j][kk] = *(const bf16x8*)&lds[BUFC][1][kk][wc * 64 + (2 + j) * 16 + r_lane][rd_col]; \
        if (DOREST) { STG(pA1, BUFC, 0, rbA1); pA1 += 64; }                   \
        ASM_BARRIER();                                                        \
        __builtin_amdgcn_s_setprio(1);                                        \
        _Pragma("unroll") for (int i = 0; i < 4; i++)                         \
        _Pragma("unroll") for (int j = 0; j < 2; j++)                         \
        _Pragma("unroll") for (int kk = 0; kk < 2; kk++)                      \
            acc[i][2 + j] = __builtin_amdgcn_mfma_f32_16x16x32_bf16(          \
                aA[i][kk], aB1[j][kk], acc[i][2 + j], 0, 0, 0);               \
        __builtin_amdgcn_s_setprio(0);                                        \
        ASM_BARRIER();                                                        \
        /* ---- p2: read aA(rows 64-127); stage B1(t+2) (dead after p0) */    \
        _Pragma("unroll") for (int i = 0; i < 4; i++)                         \
        _Pragma("unroll") for (int kk = 0; kk < 2; kk++)                      \
            aA[i][kk] = *(const bf16x8*)&lds[BUFC][0][kk][wr * 128 + (4 + i) * 16 + r_lane][rd_col]; \
        if (DOREST) { STG(pB1, BUFC, 1, rbB1); pB1 += 64; }                   \
        ASM_BARRIER();                                                        \
        __builtin_amdgcn_s_setprio(1);                                        \
        _Pragma("unroll") for (int i = 0; i < 4; i++)                         \
        _Pragma("unroll") for (int j = 0; j < 2; j++)                         \
        _Pragma("unroll") for (int kk = 0; kk < 2; kk++)                      \
            acc[4 + i][j] = __builtin_amdgcn_mfma_f32_16x16x32_bf16(          \
                aA[i][kk], aB0[j][kk], acc[4 + i][j], 0, 0, 0);               \
        __builtin_amdgcn_s_setprio(0);                                        \
        ASM_BARRIER();                                                        \
        /* ---- p3: stage B2(t+2) (dead after p1); per-tile vmcnt wait */     \
        if (DOREST) { STG(pB2, BUFC, 1, rbB2); pB2 += 64; }                   \
        ASM_BARRIER();                                                        \
        __builtin_amdgcn_s_setprio(1);                                        \
        _Pragma("unroll") for (int i = 0; i < 4; i++)                         \
        _Pragma("unroll") for (int j = 0; j < 2; j++)                         \
        _Pragma("unroll") for (int kk = 0; kk < 2; kk++)                      \
            acc[4 + i][2 + j] = __builtin_amdgcn_mfma_f32_16x16x32_bf16(      \
                aA[i][kk], aB1[j][kk], acc[4 + i][2 + j], 0, 0, 0);           \
        __builtin_amdgcn_s_setprio(0);                                        \
        /* oldest 8 outstanding = tile t+1; keep the 6 tile-(t+2) stages */   \
        asm volatile("s_waitcnt vmcnt(%0)" :: "n"(WN) : "memory");            \
        ASM_BARRIER();                                                        \
    } while (0)

    // main: t in [0, NT-4], all stage conditions true, buf = t&1 by parity
    for (int t = 0; t + 3 < NT; t += 2) {
        KTILE(0, 1, 1, 6);
        KTILE(1, 1, 1, 6);
    }
    // tails: t = NT-2 (stage only A2 for tile NT-1, then full drain), t = NT-1
    KTILE(0, 1, 0, 0);
    KTILE(1, 0, 0, 0);
#undef KTILE
#undef STG

    // ---- epilogue (verified r2 form) --------------------------------------
    const float s = *scale_p;
#pragma unroll
    for (int j = 0; j < 4; j++) {
        const int col  = n0 + wc * 64 + j * 16 + r_lane;
        const float bc = bias[col];
#pragma unroll
        for (int i = 0; i < 8; i++) {
            const int rowg = m0 + wr * 128 + i * 16 + quad * 4;
#pragma unroll
            for (int r = 0; r < 4; r++)
                Y[(size_t)(rowg + r) * N + col] = acc[i][j][r] * s + bc;
        }
    }
}

// ---------------- fallback: 128^2 DMA kernel (previous best) ---------------
__global__ __launch_bounds__(256)
void ql_gemm_bf16_dma(const bf16_t* __restrict__ X,   // [M,K] bf16
                      const bf16_t* __restrict__ W,   // [N,K] bf16
                      const float* __restrict__ bias, // [N]
                      const float* __restrict__ scale_p,
                      float* __restrict__ Y,          // [M,N]
                      int M, int N, int K)
{
    __shared__ alignas(16) bf16_t lA[BM][BK];
    __shared__ alignas(16) bf16_t lB[BN][BK];

    const int tid  = threadIdx.x;
    const int lane = tid & 63;
    const int wave = tid >> 6;            // 0..3
    const int wm   = (wave & 1) * 64;
    const int wn   = (wave >> 1) * 64;

    const int m0 = blockIdx.x * BM;
    const int n0 = blockIdx.y * BN;

    const int r_lane = lane & 15;
    const int quad   = lane >> 4;

    const int st_row = lane >> 2;
    const int st_q   = (lane & 3) ^ ((lane >> 3) & 3);
    const int st_col = st_q * 8;

    const int rd_col = (quad ^ ((r_lane >> 1) & 3)) * 8;

    f32x4 acc[4][4];
#pragma unroll
    for (int i = 0; i < 4; i++)
#pragma unroll
        for (int j = 0; j < 4; j++)
            acc[i][j] = (f32x4)0.0f;

    for (int k0 = 0; k0 < K; k0 += BK) {
#pragma unroll
        for (int i = 0; i < 2; i++) {
            const int c   = i * 4 + wave;       // chunk 0..7
            const int row = c * 16 + st_row;
            __builtin_amdgcn_global_load_lds(
                GLB_U32(X + (size_t)(m0 + row) * K + k0 + st_col),
                LDS_U32(&lA[c * 16][0]), 16, 0, 0);
            __builtin_amdgcn_global_load_lds(
                GLB_U32(W + (size_t)(n0 + row) * K + k0 + st_col),
                LDS_U32(&lB[c * 16][0]), 16, 0, 0);
        }
        __syncthreads();

        bf16x8 af[4], bfr[4];
#pragma unroll
        for (int i = 0; i < 4; i++) {
            af[i]  = *(const bf16x8*)&lA[wm + i * 16 + r_lane][rd_col];
            bfr[i] = *(const bf16x8*)&lB[wn + i * 16 + r_lane][rd_col];
        }

#pragma unroll
        for (int i = 0; i < 4; i++)
#pragma unroll
            for (int j = 0; j < 4; j++)
                acc[i][j] = __builtin_amdgcn_mfma_f32_16x16x32_bf16(
                    af[i], bfr[j], acc[i][j], 0, 0, 0);

        __syncthreads();
    }

    const float s = *scale_p;
#pragma unroll
    for (int j = 0; j < 4; j++) {
        const int col  = n0 + wn + j * 16 + r_lane;
        const float bc = bias[col];
#pragma unroll
        for (int i = 0; i < 4; i++) {
            const int rowg = m0 + wm + i * 16 + quad * 4;
#pragma unroll
            for (int r = 0; r < 4; r++)
                Y[(size_t)(rowg + r) * N + col] = acc[i][j][r] * s + bc;
        }
    }
}

// ---------------- fallback: fused-convert kernel (no workspace) ------------
__global__ __launch_bounds__(256)
void ql_gemm_bf16_fused(const float* __restrict__ X, const float* __restrict__ W,
                        const float* __restrict__ bias, const float* __restrict__ scale_p,
                        float* __restrict__ Y, int M, int N, int K)
{
    __shared__ alignas(16) bf16_t lA[BM][BK];
    __shared__ alignas(16) bf16_t lB[BN][BK];

    const int tid  = threadIdx.x;
    const int lane = tid & 63;
    const int wave = tid >> 6;
    const int wm   = (wave & 1) * 64;
    const int wn   = (wave >> 1) * 64;
    const int m0 = blockIdx.x * BM;
    const int n0 = blockIdx.y * BN;
    const int r_lane = lane & 15;
    const int quad   = lane >> 4;

    f32x4 acc[4][4];
#pragma unroll
    for (int i = 0; i < 4; i++)
#pragma unroll
        for (int j = 0; j < 4; j++) acc[i][j] = (f32x4)0.0f;

    for (int k0 = 0; k0 < K; k0 += BK) {
#pragma unroll
        for (int i = 0; i < 4; i++) {
            const int l   = tid + i * 256;
            const int row = l >> 3;
            const int c4  = (l & 7) * 4;
            const float4 xa = *(const float4*)(X + (size_t)(m0 + row) * K + k0 + c4);
            const float4 wb = *(const float4*)(W + (size_t)(n0 + row) * K + k0 + c4);
            bf16x4 xh = { (bf16_t)xa.x, (bf16_t)xa.y, (bf16_t)xa.z, (bf16_t)xa.w };
            bf16x4 wh = { (bf16_t)wb.x, (bf16_t)wb.y, (bf16_t)wb.z, (bf16_t)wb.w };
            *(bf16x4*)&lA[row][c4] = xh;
            *(bf16x4*)&lB[row][c4] = wh;
        }
        __syncthreads();
        bf16x8 af[4], bfr[4];
#pragma unroll
        for (int i = 0; i < 4; i++) {
            af[i]  = *(const bf16x8*)&lA[wm + i * 16 + r_lane][quad * 8];
            bfr[i] = *(const bf16x8*)&lB[wn + i * 16 + r_lane][quad * 8];
        }
#pragma unroll
        for (int i = 0; i < 4; i++)
#pragma unroll
            for (int j = 0; j < 4; j++)
                acc[i][j] = __builtin_amdgcn_mfma_f32_16x16x32_bf16(af[i], bfr[j], acc[i][j], 0, 0, 0);
        __syncthreads();
    }

    const float s = *scale_p;
#pragma unroll
    for (int j = 0; j < 4; j++) {
        const int col  = n0 + wn + j * 16 + r_lane;
        const float bc = bias[col];
#pragma unroll
        for (int i = 0; i < 4; i++) {
            const int rowg = m0 + wm + i * 16 + quad * 4;
#pragma unroll
            for (int r = 0; r < 4; r++)
                Y[(size_t)(rowg + r) * N + col] = acc[i][j][r] * s + bc;
        }
    }
}

extern "C" void kernel_launch(void* const* d_in, const int* in_sizes, int n_in,
                              void* d_out, int out_size, void* d_ws, size_t ws_size,
                              hipStream_t stream) {
    const float* X     = (const float*)d_in[0];
    const float* W     = (const float*)d_in[1];
    const float* bias  = (const float*)d_in[2];
    const float* scale = (const float*)d_in[3];
    float* Y           = (float*)d_out;

    const int N = in_sizes[2];
    const int K = in_sizes[1] / N;
    const int M = in_sizes[0] / K;

    const size_t x_elems = (size_t)M * K;
    const size_t w_elems = (size_t)N * K;
    const size_t need = (x_elems + w_elems) * sizeof(bf16_t);

    if (ws_size >= need) {
        bf16_t* Xb = (bf16_t*)d_ws;
        bf16_t* Wb = Xb + x_elems;
        long xn8 = (long)(x_elems / 8);
        long wn8 = (long)(w_elems / 8);
        long nthreads = xn8 + wn8;
        cvt2_f32_bf16<<<(nthreads + 255) / 256, 256, 0, stream>>>(X, Xb, xn8, W, Wb, wn8);

        if ((M % 256 == 0) && (N % 256 == 0) && (K % 128 == 0) && (K >= 256) &&
            (x_elems % 8 == 0) && (w_elems % 8 == 0)) {
            dim3 grid((M / 256) * (N / 256));
            ql_gemm_256_8ph<<<grid, 512, 0, stream>>>(Xb, Wb, bias, scale, Y, M, N, K);
        } else {
            dim3 grid(M / BM, N / BN);
            ql_gemm_bf16_dma<<<grid, 256, 0, stream>>>(Xb, Wb, bias, scale, Y, M, N, K);
        }
    } else {
        dim3 grid(M / BM, N / BN);
        ql_gemm_bf16_fused<<<grid, 256, 0, stream>>>(X, W, bias, scale, Y, M, N, K);
    }
}